// Round 17
// baseline (142.866 us; speedup 1.0000x reference)
//
#include <hip/hip_runtime.h>
#include <math.h>

namespace {
constexpr int B_ = 2, S_ = 2048, HID_ = 1024, NH_ = 16, HD_ = 64;
constexpr int M_ = B_ * S_;                 // 4096 rows
constexpr int QSZ = B_ * NH_ * S_ * HD_;    // 4194304 elements per tensor
constexpr int TBL = S_ * (HD_ / 2);         // 65536 cos/sin entries
constexpr float LOG2E = 1.4426950408889634f;

typedef float f32x4 __attribute__((ext_vector_type(4)));
typedef __bf16 bf16x8 __attribute__((ext_vector_type(8)));
typedef unsigned int u32x4 __attribute__((ext_vector_type(4)));
typedef unsigned short u16;

__device__ inline u16 f2bf(float x) {
  unsigned int u = __float_as_uint(x);
  return (u16)((u + 0x7fffu + ((u >> 16) & 1u)) >> 16);
}
__device__ inline float bf2f(u16 h) {
  return __uint_as_float(((unsigned int)h) << 16);
}

typedef __attribute__((address_space(1))) const unsigned int as1_u32;
typedef __attribute__((address_space(3))) unsigned int as3_u32;
__device__ __forceinline__ void gll16(const void* g, void* l) {
  __builtin_amdgcn_global_load_lds((as1_u32*)g, (as3_u32*)l, 16, 0, 0);
}

// gfx950 cross-lane row swaps (VALU, no LDS pipe)
__device__ __forceinline__ void swap32(unsigned int& a, unsigned int& b) {
  asm("v_permlane32_swap_b32 %0, %1" : "+v"(a), "+v"(b));
}
__device__ __forceinline__ void swap16(unsigned int& a, unsigned int& b) {
  asm("v_permlane16_swap_b32 %0, %1" : "+v"(a), "+v"(b));
}
__device__ __forceinline__ unsigned int cvtpk(float lo, float hi) {
  unsigned int r;
  asm("v_cvt_pk_bf16_f32 %0, %1, %2" : "=v"(r) : "v"(lo), "v"(hi));
  return r;
}
__device__ __forceinline__ float max3f(float a, float b, float c) {
  float r;
  asm("v_max3_f32 %0, %1, %2, %3" : "=v"(r) : "v"(a), "v"(b), "v"(c));
  return r;
}

// ---------------- fused prep: hs->bf16 | W->W^T bf16 | rope table ----------------
// flat grid: [0,4096) convert_hs, [4096,4864) transpose_w, [4864,5120) rope table
__global__ __launch_bounds__(256)
void prep_kernel(const float* __restrict__ hs, u16* __restrict__ hh,
                 const float* __restrict__ Wq, const float* __restrict__ Wk,
                 const float* __restrict__ Wv, u16* __restrict__ wt,
                 float* __restrict__ ct, float* __restrict__ st) {
  __shared__ float tile[64][65];
  const int bid = blockIdx.x;
  const int t = threadIdx.x;
  if (bid < 4096) {
    size_t e = (size_t)bid * 256 + t;
    float4 v = *(const float4*)&hs[e * 4];
    short4 hi = {(short)f2bf(v.x), (short)f2bf(v.y), (short)f2bf(v.z), (short)f2bf(v.w)};
    *(short4*)&hh[e * 4] = hi;
  } else if (bid < 4864) {
    int r = bid - 4096;
    int bx = r & 15, by = (r >> 4) & 15, bz = r >> 8;
    const float* W = bz == 0 ? Wq : bz == 1 ? Wk : Wv;
    int k0 = bx * 64, n0 = by * 64;
    int lrow = t >> 4, lcol = (t & 15) * 4;
#pragma unroll
    for (int i = 0; i < 4; ++i) {
      float4 v = *(const float4*)&W[(size_t)(k0 + lrow + i * 16) * HID_ + n0 + lcol];
      tile[lrow + i * 16][lcol + 0] = v.x;
      tile[lrow + i * 16][lcol + 1] = v.y;
      tile[lrow + i * 16][lcol + 2] = v.z;
      tile[lrow + i * 16][lcol + 3] = v.w;
    }
    __syncthreads();
    int n = t >> 2, ks = (t & 3) * 16;
    u16 tmp[16];
#pragma unroll
    for (int j = 0; j < 16; ++j) tmp[j] = f2bf(tile[ks + j][n]);
    u16* dst = &wt[((size_t)bz * 1024 + n0 + n) * 1024 + k0 + ks];
    ((uint4*)dst)[0] = ((uint4*)tmp)[0];
    ((uint4*)dst)[1] = ((uint4*)tmp)[1];
  } else {
    int e = (bid - 4864) * 256 + t;
    int s = e >> 5, i = e & 31;
    float inv = 1.0f / powf(10000.0f, (float)(2 * i) / (float)HD_);
    float ang = (float)s * inv;
    double a = (double)ang;
    ct[e] = (float)cos(a);
    st[e] = (float)sin(a);
  }
}

// ---------------- Fused QKV projection on MFMA (dbuf, counted vmcnt) ----------
__global__ __launch_bounds__(256)
void proj_gemm_kernel(const u16* __restrict__ Ah, const u16* __restrict__ Wt,
                      const float* __restrict__ bq, const float* __restrict__ bk,
                      const float* __restrict__ bv,
                      const float* __restrict__ ct, const float* __restrict__ st,
                      u16* __restrict__ qw, u16* __restrict__ kw, u16* __restrict__ vt) {
  __shared__ u16 sAh[2][128 * 64];
  __shared__ u16 sB[2][128 * 64];
  const int tid = threadIdx.x;
  const int wave = tid >> 6, lane = tid & 63;
  const int lr = lane & 15, lg = lane >> 4;

  int bid = blockIdx.x;
  int swz = (bid & 7) * 96 + (bid >> 3);
  const int gx = swz / 24, gy = swz % 24;
  const int m0 = gx * 128;
  const int ng0 = gy * 128;

  size_t aoff[4], boff[4];
  int c16[4];
#pragma unroll
  for (int i = 0; i < 4; ++i) {
    int c = i * 256 + tid;
    int row = c >> 3, ks = c & 7;
    int kph = (ks ^ (row & 7)) * 8;
    aoff[i] = (size_t)(m0 + row) * HID_ + kph;
    boff[i] = (size_t)(ng0 + row) * HID_ + kph;
    c16[i] = c * 16;
  }

  const int wr = (wave >> 1) * 64, wc = (wave & 1) * 64;
  int offA[4][2], offB[4][2];
#pragma unroll
  for (int f = 0; f < 4; ++f) {
    int ra = wr + f * 16 + lr;
    int rb = wc + f * 16 + lr;
#pragma unroll
    for (int kk = 0; kk < 2; ++kk) {
      offA[f][kk] = ra * 128 + (((kk * 4 + lg)) ^ (ra & 7)) * 16;
      offB[f][kk] = rb * 128 + (((kk * 4 + lg)) ^ (rb & 7)) * 16;
    }
  }

  f32x4 acc[4][4];
#pragma unroll
  for (int mf = 0; mf < 4; ++mf)
#pragma unroll
    for (int nf = 0; nf < 4; ++nf) acc[mf][nf] = (f32x4){0.f, 0.f, 0.f, 0.f};

  // prologue: stage K-step 0 into buffer 0
#pragma unroll
  for (int i = 0; i < 4; ++i) {
    gll16(Ah + aoff[i], (char*)sAh[0] + c16[i]);
    gll16(Wt + boff[i], (char*)sB[0] + c16[i]);
  }
  __syncthreads();

  for (int t = 0; t < 16; ++t) {
    if (t < 15) {
      const int nb = (t + 1) & 1;
      const int k0n = (t + 1) * 64;
#pragma unroll
      for (int i = 0; i < 4; ++i) {
        gll16(Ah + aoff[i] + k0n, (char*)sAh[nb] + c16[i]);
        gll16(Wt + boff[i] + k0n, (char*)sB[nb] + c16[i]);
      }
      asm volatile("s_waitcnt vmcnt(8)" ::: "memory");
    } else {
      asm volatile("s_waitcnt vmcnt(0)" ::: "memory");
    }
    __builtin_amdgcn_s_barrier();
    __builtin_amdgcn_sched_barrier(0);

    const char* sa = (const char*)sAh[t & 1];
    const char* sb = (const char*)sB[t & 1];
#pragma unroll
    for (int kk = 0; kk < 2; ++kk) {
      bf16x8 a_h[4], bb[4];
#pragma unroll
      for (int f = 0; f < 4; ++f) {
        a_h[f] = *(const bf16x8*)(sa + offA[f][kk]);
        bb[f] = *(const bf16x8*)(sb + offB[f][kk]);
      }
      __builtin_amdgcn_s_setprio(1);
#pragma unroll
      for (int mf = 0; mf < 4; ++mf)
#pragma unroll
        for (int nf = 0; nf < 4; ++nf)
          acc[mf][nf] = __builtin_amdgcn_mfma_f32_16x16x32_bf16(a_h[mf], bb[nf], acc[mf][nf], 0, 0, 0);
      __builtin_amdgcn_s_setprio(0);
    }
    __builtin_amdgcn_sched_barrier(0);
    __builtin_amdgcn_s_barrier();
  }

  const int which = gy >> 3;
  const int colm = (gy & 7) * 128 + wc;
  const int h = colm >> 6;
  const float* bias = which == 0 ? bq : which == 1 ? bk : bv;
  // Q folds HD^-0.5 AND log2(e) for the exp2-domain softmax
  const float scale = which == 0 ? 0.125f * LOG2E : 1.0f;

  if (which < 2) {
    u16* oh = which == 0 ? qw : kw;
#pragma unroll
    for (int mf = 0; mf < 4; ++mf) {
#pragma unroll
      for (int r = 0; r < 4; ++r) {
        int m = m0 + wr + mf * 16 + lg * 4 + r;
        int b = m >> 11, s = m & (S_ - 1);
        size_t rowb = (((size_t)b * NH_ + h) * S_ + s) * HD_;
#pragma unroll
        for (int nf = 0; nf < 2; ++nf) {
          int d = nf * 16 + lr;
          float x1 = acc[mf][nf][r] + bias[colm + d];
          float x2 = acc[mf][nf + 2][r] + bias[colm + d + 32];
          float cth = ct[s * 32 + d], sth = st[s * 32 + d];
          oh[rowb + d]      = f2bf((x1 * cth - x2 * sth) * scale);
          oh[rowb + d + 32] = f2bf((x2 * cth + x1 * sth) * scale);
        }
      }
    }
  } else {
#pragma unroll
    for (int mf = 0; mf < 4; ++mf) {
      int mB = m0 + wr + mf * 16 + lg * 4;
      int b = mB >> 11, s0 = mB & (S_ - 1);
#pragma unroll
      for (int nf = 0; nf < 4; ++nf) {
        int d = nf * 16 + lr;
        float bi = bias[colm + d];
        ushort4 pk;
        pk.x = f2bf(acc[mf][nf][0] + bi);
        pk.y = f2bf(acc[mf][nf][1] + bi);
        pk.z = f2bf(acc[mf][nf][2] + bi);
        pk.w = f2bf(acc[mf][nf][3] + bi);
        *(ushort4*)&vt[(((size_t)b * NH_ + h) * HD_ + d) * S_ + s0] = pk;
      }
    }
  }
}

// ---------------- Flash attention: R16 body + T14 async-STAGE split ----
// Staging is now global->reg (issued one compute-phase early) -> ds_write.
// Same LDS layout/content as R16; sync is __syncthreads-only (2 per tile).
// LDS: K [128 kv][64 d] @0 (16K), V^T [64 d][128 kv] @16K, mask*log2e @32K (8K).
__global__ __launch_bounds__(256, 2)
void attn_mfma_kernel(const u16* __restrict__ qw, const u16* __restrict__ kw,
                      const u16* __restrict__ vt, const float* __restrict__ mask,
                      float* __restrict__ outp) {
  __shared__ __align__(16) char smem[40960];
  constexpr int VTB = 16384, MS = 32768;
  const int tid = threadIdx.x;
  const int wave = tid >> 6, lane = tid & 63;
  const int lr = lane & 15, lg = lane >> 4;

  // XCD-chunked: 512 blocks, each XCD owns 4 heads x 16 q-tiles
  const int bid = blockIdx.x;
  const int idx = bid >> 3;
  const int bh = (bid & 7) * 4 + (idx >> 4);
  const int q0 = (idx & 15) * 128;
  const int b = bh >> 4, h = bh & 15;
  const size_t hb = (size_t)bh * S_ * HD_;

  // stage mask row scaled by log2(e) (8KB)
  {
    const float* mrow = mask + (size_t)b * S_ + tid * 8;
    float4 v0 = *(const float4*)mrow;
    float4 v1 = *(const float4*)(mrow + 4);
    v0.x *= LOG2E; v0.y *= LOG2E; v0.z *= LOG2E; v0.w *= LOG2E;
    v1.x *= LOG2E; v1.y *= LOG2E; v1.z *= LOG2E; v1.w *= LOG2E;
    *(float4*)(smem + MS + tid * 32) = v0;
    *(float4*)(smem + MS + tid * 32 + 16) = v1;
  }

  // Q fragments (B-operand): lane holds Q[q0 + wave*32 + qb*16 + lr][t*32 + lg*8 + j]
  bf16x8 aq[2][2];
#pragma unroll
  for (int qb = 0; qb < 2; ++qb) {
    size_t base = hb + (size_t)(q0 + wave * 32 + qb * 16 + lr) * HD_ + lg * 8;
    aq[qb][0] = *(const bf16x8*)&qw[base];
    aq[qb][1] = *(const bf16x8*)&qw[base + 32];
  }

  // ones A-fragment (row 0 = 1s) for l = sum(P) via MFMA
  bf16x8 ones_f;
  {
    unsigned int w = (lr == 0) ? 0x3F803F80u : 0u;
    u32x4 f = {w, w, w, w};
    ones_f = *(bf16x8*)&f;
  }

  f32x4 O[2][4], O4[2];
  float mrun[2];
#pragma unroll
  for (int qb = 0; qb < 2; ++qb) {
    mrun[qb] = -INFINITY;
    O4[qb] = (f32x4){0.f, 0.f, 0.f, 0.f};
#pragma unroll
    for (int dt = 0; dt < 4; ++dt) O[qb][dt] = (f32x4){0.f, 0.f, 0.f, 0.f};
  }

  // staging offsets (global source pre-swizzled, LDS dest linear) — same
  // placement as R16's gll16 path, now via regs.
  size_t kgo[4], vgo[4];
  int klo_[4], vlo_[4];
#pragma unroll
  for (int i = 0; i < 4; ++i) {
    int a = i * 4096 + tid * 16;
    {
      int row = a >> 7, seg = (a >> 4) & 7;
      kgo[i] = (size_t)row * HD_ + ((seg ^ (row & 7)) * 8);
      klo_[i] = a;
    }
    {
      int row = a >> 8, seg = (a >> 4) & 15;
      int sg = (seg & 8) | ((seg & 7) ^ (row & 7));
      vgo[i] = (size_t)row * S_ + sg * 8;
      vlo_[i] = VTB + a;
    }
  }

  const int sw = (lr & 7) << 4;

  uint4 kreg[4], vreg[4];
  // prologue: issue loads for tile 0
#pragma unroll
  for (int i = 0; i < 4; ++i) {
    kreg[i] = *(const uint4*)(kw + hb + kgo[i]);
    vreg[i] = *(const uint4*)(vt + hb + vgo[i]);
  }
  __syncthreads();  // mask stores visible before first compute

  for (int t = 0; t < 16; ++t) {
    const int k0 = t * 128;
    // write current tile's regs to LDS (compiler waits the loads here)
#pragma unroll
    for (int i = 0; i < 4; ++i) {
      *(uint4*)(smem + klo_[i]) = kreg[i];
      *(uint4*)(smem + vlo_[i]) = vreg[i];
    }
    // issue NEXT tile's loads — latency hides under this tile's compute
    if (t < 15) {
      const size_t kn = (size_t)(k0 + 128);
#pragma unroll
      for (int i = 0; i < 4; ++i) {
        kreg[i] = *(const uint4*)(kw + hb + kgo[i] + kn * HD_);
        vreg[i] = *(const uint4*)(vt + hb + vgo[i] + kn);
      }
    }
    __syncthreads();  // LDS writes visible

    // mask fragments (separate LDS region, never overwritten)
    f32x4 mk[8];
#pragma unroll
    for (int c = 0; c < 8; ++c)
      mk[c] = *(const f32x4*)(smem + MS + (k0 + c * 16 + lg * 4) * 4);

    // S^T = K Q^T + mask : mask enters through the MFMA C-operand (exact).
    f32x4 sc[2][8];
#pragma unroll
    for (int qb = 0; qb < 2; ++qb)
#pragma unroll
      for (int c = 0; c < 8; ++c) sc[qb][c] = mk[c];
    __builtin_amdgcn_s_setprio(1);
#pragma unroll
    for (int t2 = 0; t2 < 2; ++t2) {
#pragma unroll
      for (int c = 0; c < 8; ++c) {
        int off = ((c * 16 + lr) << 7) + ((t2 * 64 + lg * 16) ^ sw);
        bf16x8 kf = *(const bf16x8*)(smem + off);
        sc[0][c] = __builtin_amdgcn_mfma_f32_16x16x32_bf16(kf, aq[0][t2], sc[0][c], 0, 0, 0);
        sc[1][c] = __builtin_amdgcn_mfma_f32_16x16x32_bf16(kf, aq[1][t2], sc[1][c], 0, 0, 0);
      }
    }
    __builtin_amdgcn_s_setprio(0);

    // softmax (exp2 domain) + in-register P-fragment build
    bf16x8 pf[2][4];
#pragma unroll
    for (int qb = 0; qb < 2; ++qb) {
      float mx = -INFINITY;
#pragma unroll
      for (int c = 0; c < 8; ++c) {
        mx = max3f(mx, sc[qb][c][0], sc[qb][c][1]);
        mx = max3f(mx, sc[qb][c][2], sc[qb][c][3]);
      }
      mx = fmaxf(mx, __shfl_xor(mx, 16));
      mx = fmaxf(mx, __shfl_xor(mx, 32));
      if (mx > mrun[qb] + 8.f) {          // defer-max: tolerate p up to 2^8
        float corr = __builtin_amdgcn_exp2f(mrun[qb] - mx);
        mrun[qb] = mx;
        O4[qb] *= corr;
#pragma unroll
        for (int dt = 0; dt < 4; ++dt) O[qb][dt] *= corr;
      }
#pragma unroll
      for (int c = 0; c < 8; ++c)
#pragma unroll
        for (int r = 0; r < 4; ++r)
          sc[qb][c][r] = __builtin_amdgcn_exp2f(sc[qb][c][r] - mrun[qb]);

      // pack P (bf16 pairs) then redistribute: lane lg gets kv = kt*32 + lg*8 + j
#pragma unroll
      for (int kt = 0; kt < 4; ++kt) {
        unsigned int x0 = cvtpk(sc[qb][2 * kt][0], sc[qb][2 * kt][1]);
        unsigned int x1 = cvtpk(sc[qb][2 * kt + 1][0], sc[qb][2 * kt + 1][1]);
        unsigned int y0 = cvtpk(sc[qb][2 * kt][2], sc[qb][2 * kt][3]);
        unsigned int y1 = cvtpk(sc[qb][2 * kt + 1][2], sc[qb][2 * kt + 1][3]);
        swap32(x0, x1);
        swap16(x0, x1);
        swap32(y0, y1);
        swap16(y0, y1);
        u32x4 f = {x0, y0, x1, y1};
        pf[qb][kt] = *(bf16x8*)&f;
      }
    }

    // O^T += V^T P^T ; l accumulated as row 0 of the ones-MFMA
    __builtin_amdgcn_s_setprio(1);
#pragma unroll
    for (int kt = 0; kt < 4; ++kt) {
      O4[0] = __builtin_amdgcn_mfma_f32_16x16x32_bf16(ones_f, pf[0][kt], O4[0], 0, 0, 0);
      O4[1] = __builtin_amdgcn_mfma_f32_16x16x32_bf16(ones_f, pf[1][kt], O4[1], 0, 0, 0);
#pragma unroll
      for (int dt = 0; dt < 4; ++dt) {
        int off = VTB + ((dt * 16 + lr) << 8) + ((kt * 64 + lg * 16) ^ sw);
        bf16x8 vf = *(const bf16x8*)(smem + off);
        O[0][dt] = __builtin_amdgcn_mfma_f32_16x16x32_bf16(vf, pf[0][kt], O[0][dt], 0, 0, 0);
        O[1][dt] = __builtin_amdgcn_mfma_f32_16x16x32_bf16(vf, pf[1][kt], O[1][dt], 0, 0, 0);
      }
    }
    __builtin_amdgcn_s_setprio(0);

    __syncthreads();  // all LDS reads done before next tile's ds_write
  }

  // epilogue: l = O4 row0 (lives at lg==0, reg 0, col=q) -> broadcast via shfl
#pragma unroll
  for (int qb = 0; qb < 2; ++qb) {
    float l = __shfl(O4[qb][0], lr, 64);
    float inv = 1.0f / l;
    int s = q0 + wave * 32 + qb * 16 + lr;
    size_t rowb = ((size_t)b * S_ + s) * HID_ + h * HD_;
#pragma unroll
    for (int dt = 0; dt < 4; ++dt) {
      float4 r;
      r.x = O[qb][dt][0] * inv;
      r.y = O[qb][dt][1] * inv;
      r.z = O[qb][dt][2] * inv;
      r.w = O[qb][dt][3] * inv;
      *(float4*)&outp[rowb + dt * 16 + lg * 4] = r;
    }
  }
}

}  // namespace

extern "C" void kernel_launch(void* const* d_in, const int* in_sizes, int n_in,
                              void* d_out, int out_size, void* d_ws, size_t ws_size,
                              hipStream_t stream) {
  const float* hs   = (const float*)d_in[0];
  const float* mask = (const float*)d_in[1];
  const float* Wq   = (const float*)d_in[2];
  const float* bq   = (const float*)d_in[3];
  const float* Wk   = (const float*)d_in[4];
  const float* bk   = (const float*)d_in[5];
  const float* Wv   = (const float*)d_in[6];
  const float* bv   = (const float*)d_in[7];

  u16* qw = (u16*)d_ws;                  // [B,NH,S,HD] bf16 (rope + scale*log2e)
  u16* kw = qw + QSZ;                    // [B,NH,S,HD] bf16 (rope)
  u16* vt = kw + QSZ;                    // [B,NH,HD,S] bf16
  u16* hh = vt + QSZ;                    // [M, HID] bf16
  u16* wt = hh + (size_t)M_ * HID_;      // [3][1024][1024] transposed bf16
  float* ct = (float*)(wt + (size_t)3 * 1024 * 1024);
  float* st = ct + TBL;

  prep_kernel<<<5120, 256, 0, stream>>>(hs, hh, Wq, Wk, Wv, wt, ct, st);

  proj_gemm_kernel<<<768, 256, 0, stream>>>(hh, wt, bq, bk, bv, ct, st, qw, kw, vt);

  attn_mfma_kernel<<<512, 256, 0, stream>>>(qw, kw, vt, mask, (float*)d_out);
}

// Round 18
// 103.216 us; speedup vs baseline: 1.3841x; 1.3841x over previous
//
#include <hip/hip_runtime.h>
#include <math.h>

namespace {
constexpr int B_ = 2, S_ = 2048, HID_ = 1024, NH_ = 16, HD_ = 64;
constexpr int M_ = B_ * S_;                 // 4096 rows
constexpr int QSZ = B_ * NH_ * S_ * HD_;    // 4194304 elements per tensor
constexpr int TBL = S_ * (HD_ / 2);         // 65536 cos/sin entries
constexpr float LOG2E = 1.4426950408889634f;

typedef float f32x4 __attribute__((ext_vector_type(4)));
typedef __bf16 bf16x8 __attribute__((ext_vector_type(8)));
typedef unsigned int u32x4 __attribute__((ext_vector_type(4)));
typedef unsigned short u16;

__device__ inline u16 f2bf(float x) {
  unsigned int u = __float_as_uint(x);
  return (u16)((u + 0x7fffu + ((u >> 16) & 1u)) >> 16);
}
__device__ inline float bf2f(u16 h) {
  return __uint_as_float(((unsigned int)h) << 16);
}

typedef __attribute__((address_space(1))) const unsigned int as1_u32;
typedef __attribute__((address_space(3))) unsigned int as3_u32;
__device__ __forceinline__ void gll16(const void* g, void* l) {
  __builtin_amdgcn_global_load_lds((as1_u32*)g, (as3_u32*)l, 16, 0, 0);
}

// gfx950 cross-lane row swaps (VALU, no LDS pipe)
__device__ __forceinline__ void swap32(unsigned int& a, unsigned int& b) {
  asm("v_permlane32_swap_b32 %0, %1" : "+v"(a), "+v"(b));
}
__device__ __forceinline__ void swap16(unsigned int& a, unsigned int& b) {
  asm("v_permlane16_swap_b32 %0, %1" : "+v"(a), "+v"(b));
}
__device__ __forceinline__ unsigned int cvtpk(float lo, float hi) {
  unsigned int r;
  asm("v_cvt_pk_bf16_f32 %0, %1, %2" : "=v"(r) : "v"(lo), "v"(hi));
  return r;
}
__device__ __forceinline__ float max3f(float a, float b, float c) {
  float r;
  asm("v_max3_f32 %0, %1, %2, %3" : "=v"(r) : "v"(a), "v"(b), "v"(c));
  return r;
}

// ---------------- fused prep: hs->bf16 | W->W^T bf16 | rope table ----------------
// flat grid: [0,4096) convert_hs, [4096,4864) transpose_w, [4864,5120) rope table
__global__ __launch_bounds__(256)
void prep_kernel(const float* __restrict__ hs, u16* __restrict__ hh,
                 const float* __restrict__ Wq, const float* __restrict__ Wk,
                 const float* __restrict__ Wv, u16* __restrict__ wt,
                 float* __restrict__ ct, float* __restrict__ st) {
  __shared__ float tile[64][65];
  const int bid = blockIdx.x;
  const int t = threadIdx.x;
  if (bid < 4096) {
    size_t e = (size_t)bid * 256 + t;
    float4 v = *(const float4*)&hs[e * 4];
    short4 hi = {(short)f2bf(v.x), (short)f2bf(v.y), (short)f2bf(v.z), (short)f2bf(v.w)};
    *(short4*)&hh[e * 4] = hi;
  } else if (bid < 4864) {
    int r = bid - 4096;
    int bx = r & 15, by = (r >> 4) & 15, bz = r >> 8;
    const float* W = bz == 0 ? Wq : bz == 1 ? Wk : Wv;
    int k0 = bx * 64, n0 = by * 64;
    int lrow = t >> 4, lcol = (t & 15) * 4;
#pragma unroll
    for (int i = 0; i < 4; ++i) {
      float4 v = *(const float4*)&W[(size_t)(k0 + lrow + i * 16) * HID_ + n0 + lcol];
      tile[lrow + i * 16][lcol + 0] = v.x;
      tile[lrow + i * 16][lcol + 1] = v.y;
      tile[lrow + i * 16][lcol + 2] = v.z;
      tile[lrow + i * 16][lcol + 3] = v.w;
    }
    __syncthreads();
    int n = t >> 2, ks = (t & 3) * 16;
    u16 tmp[16];
#pragma unroll
    for (int j = 0; j < 16; ++j) tmp[j] = f2bf(tile[ks + j][n]);
    u16* dst = &wt[((size_t)bz * 1024 + n0 + n) * 1024 + k0 + ks];
    ((uint4*)dst)[0] = ((uint4*)tmp)[0];
    ((uint4*)dst)[1] = ((uint4*)tmp)[1];
  } else {
    int e = (bid - 4864) * 256 + t;
    int s = e >> 5, i = e & 31;
    float inv = 1.0f / powf(10000.0f, (float)(2 * i) / (float)HD_);
    float ang = (float)s * inv;
    double a = (double)ang;
    ct[e] = (float)cos(a);
    st[e] = (float)sin(a);
  }
}

// ---------------- Fused QKV projection on MFMA (dbuf, counted vmcnt) ----------
__global__ __launch_bounds__(256)
void proj_gemm_kernel(const u16* __restrict__ Ah, const u16* __restrict__ Wt,
                      const float* __restrict__ bq, const float* __restrict__ bk,
                      const float* __restrict__ bv,
                      const float* __restrict__ ct, const float* __restrict__ st,
                      u16* __restrict__ qw, u16* __restrict__ kw, u16* __restrict__ vt) {
  __shared__ u16 sAh[2][128 * 64];
  __shared__ u16 sB[2][128 * 64];
  const int tid = threadIdx.x;
  const int wave = tid >> 6, lane = tid & 63;
  const int lr = lane & 15, lg = lane >> 4;

  int bid = blockIdx.x;
  int swz = (bid & 7) * 96 + (bid >> 3);
  const int gx = swz / 24, gy = swz % 24;
  const int m0 = gx * 128;
  const int ng0 = gy * 128;

  size_t aoff[4], boff[4];
  int c16[4];
#pragma unroll
  for (int i = 0; i < 4; ++i) {
    int c = i * 256 + tid;
    int row = c >> 3, ks = c & 7;
    int kph = (ks ^ (row & 7)) * 8;
    aoff[i] = (size_t)(m0 + row) * HID_ + kph;
    boff[i] = (size_t)(ng0 + row) * HID_ + kph;
    c16[i] = c * 16;
  }

  const int wr = (wave >> 1) * 64, wc = (wave & 1) * 64;
  int offA[4][2], offB[4][2];
#pragma unroll
  for (int f = 0; f < 4; ++f) {
    int ra = wr + f * 16 + lr;
    int rb = wc + f * 16 + lr;
#pragma unroll
    for (int kk = 0; kk < 2; ++kk) {
      offA[f][kk] = ra * 128 + (((kk * 4 + lg)) ^ (ra & 7)) * 16;
      offB[f][kk] = rb * 128 + (((kk * 4 + lg)) ^ (rb & 7)) * 16;
    }
  }

  f32x4 acc[4][4];
#pragma unroll
  for (int mf = 0; mf < 4; ++mf)
#pragma unroll
    for (int nf = 0; nf < 4; ++nf) acc[mf][nf] = (f32x4){0.f, 0.f, 0.f, 0.f};

  // prologue: stage K-step 0 into buffer 0
#pragma unroll
  for (int i = 0; i < 4; ++i) {
    gll16(Ah + aoff[i], (char*)sAh[0] + c16[i]);
    gll16(Wt + boff[i], (char*)sB[0] + c16[i]);
  }
  __syncthreads();

  for (int t = 0; t < 16; ++t) {
    if (t < 15) {
      const int nb = (t + 1) & 1;
      const int k0n = (t + 1) * 64;
#pragma unroll
      for (int i = 0; i < 4; ++i) {
        gll16(Ah + aoff[i] + k0n, (char*)sAh[nb] + c16[i]);
        gll16(Wt + boff[i] + k0n, (char*)sB[nb] + c16[i]);
      }
      asm volatile("s_waitcnt vmcnt(8)" ::: "memory");
    } else {
      asm volatile("s_waitcnt vmcnt(0)" ::: "memory");
    }
    __builtin_amdgcn_s_barrier();
    __builtin_amdgcn_sched_barrier(0);

    const char* sa = (const char*)sAh[t & 1];
    const char* sb = (const char*)sB[t & 1];
#pragma unroll
    for (int kk = 0; kk < 2; ++kk) {
      bf16x8 a_h[4], bb[4];
#pragma unroll
      for (int f = 0; f < 4; ++f) {
        a_h[f] = *(const bf16x8*)(sa + offA[f][kk]);
        bb[f] = *(const bf16x8*)(sb + offB[f][kk]);
      }
      __builtin_amdgcn_s_setprio(1);
#pragma unroll
      for (int mf = 0; mf < 4; ++mf)
#pragma unroll
        for (int nf = 0; nf < 4; ++nf)
          acc[mf][nf] = __builtin_amdgcn_mfma_f32_16x16x32_bf16(a_h[mf], bb[nf], acc[mf][nf], 0, 0, 0);
      __builtin_amdgcn_s_setprio(0);
    }
    __builtin_amdgcn_sched_barrier(0);
    __builtin_amdgcn_s_barrier();
  }

  const int which = gy >> 3;
  const int colm = (gy & 7) * 128 + wc;
  const int h = colm >> 6;
  const float* bias = which == 0 ? bq : which == 1 ? bk : bv;
  // Q folds HD^-0.5 AND log2(e) for the exp2-domain softmax
  const float scale = which == 0 ? 0.125f * LOG2E : 1.0f;

  if (which < 2) {
    u16* oh = which == 0 ? qw : kw;
#pragma unroll
    for (int mf = 0; mf < 4; ++mf) {
#pragma unroll
      for (int r = 0; r < 4; ++r) {
        int m = m0 + wr + mf * 16 + lg * 4 + r;
        int b = m >> 11, s = m & (S_ - 1);
        size_t rowb = (((size_t)b * NH_ + h) * S_ + s) * HD_;
#pragma unroll
        for (int nf = 0; nf < 2; ++nf) {
          int d = nf * 16 + lr;
          float x1 = acc[mf][nf][r] + bias[colm + d];
          float x2 = acc[mf][nf + 2][r] + bias[colm + d + 32];
          float cth = ct[s * 32 + d], sth = st[s * 32 + d];
          oh[rowb + d]      = f2bf((x1 * cth - x2 * sth) * scale);
          oh[rowb + d + 32] = f2bf((x2 * cth + x1 * sth) * scale);
        }
      }
    }
  } else {
#pragma unroll
    for (int mf = 0; mf < 4; ++mf) {
      int mB = m0 + wr + mf * 16 + lg * 4;
      int b = mB >> 11, s0 = mB & (S_ - 1);
#pragma unroll
      for (int nf = 0; nf < 4; ++nf) {
        int d = nf * 16 + lr;
        float bi = bias[colm + d];
        ushort4 pk;
        pk.x = f2bf(acc[mf][nf][0] + bi);
        pk.y = f2bf(acc[mf][nf][1] + bi);
        pk.z = f2bf(acc[mf][nf][2] + bi);
        pk.w = f2bf(acc[mf][nf][3] + bi);
        *(ushort4*)&vt[(((size_t)b * NH_ + h) * HD_ + d) * S_ + s0] = pk;
      }
    }
  }
}

// ---------------- Flash attention: swapped QK^T, exp2 softmax, l-via-MFMA ----
// R16-exact (session best): KVBLK=128, 2 qb/wave, gll16 staging, mask-in-C,
// v_max3 row-max, single-buffered, __syncthreads-only.
// LDS: K [128 kv][64 d] @0 (16K), V^T [64 d][128 kv] @16K, mask*log2e @32K (8K).
__global__ __launch_bounds__(256, 2)
void attn_mfma_kernel(const u16* __restrict__ qw, const u16* __restrict__ kw,
                      const u16* __restrict__ vt, const float* __restrict__ mask,
                      float* __restrict__ outp) {
  __shared__ __align__(16) char smem[40960];
  constexpr int VTB = 16384, MS = 32768;
  const int tid = threadIdx.x;
  const int wave = tid >> 6, lane = tid & 63;
  const int lr = lane & 15, lg = lane >> 4;

  // XCD-chunked: 512 blocks, each XCD owns 4 heads x 16 q-tiles
  const int bid = blockIdx.x;
  const int idx = bid >> 3;
  const int bh = (bid & 7) * 4 + (idx >> 4);
  const int q0 = (idx & 15) * 128;
  const int b = bh >> 4, h = bh & 15;
  const size_t hb = (size_t)bh * S_ * HD_;

  // stage mask row scaled by log2(e) (8KB)
  {
    const float* mrow = mask + (size_t)b * S_ + tid * 8;
    float4 v0 = *(const float4*)mrow;
    float4 v1 = *(const float4*)(mrow + 4);
    v0.x *= LOG2E; v0.y *= LOG2E; v0.z *= LOG2E; v0.w *= LOG2E;
    v1.x *= LOG2E; v1.y *= LOG2E; v1.z *= LOG2E; v1.w *= LOG2E;
    *(float4*)(smem + MS + tid * 32) = v0;
    *(float4*)(smem + MS + tid * 32 + 16) = v1;
  }

  // Q fragments (B-operand): lane holds Q[q0 + wave*32 + qb*16 + lr][t*32 + lg*8 + j]
  bf16x8 aq[2][2];
#pragma unroll
  for (int qb = 0; qb < 2; ++qb) {
    size_t base = hb + (size_t)(q0 + wave * 32 + qb * 16 + lr) * HD_ + lg * 8;
    aq[qb][0] = *(const bf16x8*)&qw[base];
    aq[qb][1] = *(const bf16x8*)&qw[base + 32];
  }

  // ones A-fragment (row 0 = 1s) for l = sum(P) via MFMA
  bf16x8 ones_f;
  {
    unsigned int w = (lr == 0) ? 0x3F803F80u : 0u;
    u32x4 f = {w, w, w, w};
    ones_f = *(bf16x8*)&f;
  }

  f32x4 O[2][4], O4[2];
  float mrun[2];
#pragma unroll
  for (int qb = 0; qb < 2; ++qb) {
    mrun[qb] = -INFINITY;
    O4[qb] = (f32x4){0.f, 0.f, 0.f, 0.f};
#pragma unroll
    for (int dt = 0; dt < 4; ++dt) O[qb][dt] = (f32x4){0.f, 0.f, 0.f, 0.f};
  }

  // staging offsets (global source pre-swizzled, LDS dest linear)
  size_t kgo[4], vgo[4];
  int klo_[4], vlo_[4];
#pragma unroll
  for (int i = 0; i < 4; ++i) {
    int a = i * 4096 + tid * 16;
    {
      int row = a >> 7, seg = (a >> 4) & 7;
      kgo[i] = (size_t)row * HD_ + ((seg ^ (row & 7)) * 8);
      klo_[i] = a;
    }
    {
      int row = a >> 8, seg = (a >> 4) & 15;
      int sg = (seg & 8) | ((seg & 7) ^ (row & 7));
      vgo[i] = (size_t)row * S_ + sg * 8;
      vlo_[i] = VTB + a;
    }
  }

  const int sw = (lr & 7) << 4;

  for (int k0 = 0; k0 < S_; k0 += 128) {
    __syncthreads();
#pragma unroll
    for (int i = 0; i < 4; ++i) {
      gll16(kw + hb + kgo[i] + (size_t)k0 * HD_, smem + klo_[i]);
      gll16(vt + hb + vgo[i] + k0, smem + vlo_[i]);
    }
    __syncthreads();

    // mask fragments (separate LDS region, never overwritten)
    f32x4 mk[8];
#pragma unroll
    for (int c = 0; c < 8; ++c)
      mk[c] = *(const f32x4*)(smem + MS + (k0 + c * 16 + lg * 4) * 4);

    // S^T = K Q^T + mask : mask enters through the MFMA C-operand (exact).
    // lane gets S[q=lr][kv = c*16 + lg*4 + r]
    f32x4 sc[2][8];
#pragma unroll
    for (int qb = 0; qb < 2; ++qb)
#pragma unroll
      for (int c = 0; c < 8; ++c) sc[qb][c] = mk[c];
    __builtin_amdgcn_s_setprio(1);
#pragma unroll
    for (int t2 = 0; t2 < 2; ++t2) {
#pragma unroll
      for (int c = 0; c < 8; ++c) {
        int off = ((c * 16 + lr) << 7) + ((t2 * 64 + lg * 16) ^ sw);
        bf16x8 kf = *(const bf16x8*)(smem + off);
        sc[0][c] = __builtin_amdgcn_mfma_f32_16x16x32_bf16(kf, aq[0][t2], sc[0][c], 0, 0, 0);
        sc[1][c] = __builtin_amdgcn_mfma_f32_16x16x32_bf16(kf, aq[1][t2], sc[1][c], 0, 0, 0);
      }
    }
    __builtin_amdgcn_s_setprio(0);

    // softmax (exp2 domain) + in-register P-fragment build
    bf16x8 pf[2][4];
#pragma unroll
    for (int qb = 0; qb < 2; ++qb) {
      float mx = -INFINITY;
#pragma unroll
      for (int c = 0; c < 8; ++c) {
        mx = max3f(mx, sc[qb][c][0], sc[qb][c][1]);
        mx = max3f(mx, sc[qb][c][2], sc[qb][c][3]);
      }
      mx = fmaxf(mx, __shfl_xor(mx, 16));
      mx = fmaxf(mx, __shfl_xor(mx, 32));
      if (mx > mrun[qb] + 8.f) {          // defer-max: tolerate p up to 2^8
        float corr = __builtin_amdgcn_exp2f(mrun[qb] - mx);
        mrun[qb] = mx;
        O4[qb] *= corr;
#pragma unroll
        for (int dt = 0; dt < 4; ++dt) O[qb][dt] *= corr;
      }
#pragma unroll
      for (int c = 0; c < 8; ++c)
#pragma unroll
        for (int r = 0; r < 4; ++r)
          sc[qb][c][r] = __builtin_amdgcn_exp2f(sc[qb][c][r] - mrun[qb]);

      // pack P (bf16 pairs) then redistribute: lane lg gets kv = kt*32 + lg*8 + j
#pragma unroll
      for (int kt = 0; kt < 4; ++kt) {
        unsigned int x0 = cvtpk(sc[qb][2 * kt][0], sc[qb][2 * kt][1]);
        unsigned int x1 = cvtpk(sc[qb][2 * kt + 1][0], sc[qb][2 * kt + 1][1]);
        unsigned int y0 = cvtpk(sc[qb][2 * kt][2], sc[qb][2 * kt][3]);
        unsigned int y1 = cvtpk(sc[qb][2 * kt + 1][2], sc[qb][2 * kt + 1][3]);
        swap32(x0, x1);
        swap16(x0, x1);
        swap32(y0, y1);
        swap16(y0, y1);
        u32x4 f = {x0, y0, x1, y1};
        pf[qb][kt] = *(bf16x8*)&f;
      }
    }

    // O^T += V^T P^T ; l accumulated as row 0 of the ones-MFMA
    __builtin_amdgcn_s_setprio(1);
#pragma unroll
    for (int kt = 0; kt < 4; ++kt) {
      O4[0] = __builtin_amdgcn_mfma_f32_16x16x32_bf16(ones_f, pf[0][kt], O4[0], 0, 0, 0);
      O4[1] = __builtin_amdgcn_mfma_f32_16x16x32_bf16(ones_f, pf[1][kt], O4[1], 0, 0, 0);
#pragma unroll
      for (int dt = 0; dt < 4; ++dt) {
        int off = VTB + ((dt * 16 + lr) << 8) + ((kt * 64 + lg * 16) ^ sw);
        bf16x8 vf = *(const bf16x8*)(smem + off);
        O[0][dt] = __builtin_amdgcn_mfma_f32_16x16x32_bf16(vf, pf[0][kt], O[0][dt], 0, 0, 0);
        O[1][dt] = __builtin_amdgcn_mfma_f32_16x16x32_bf16(vf, pf[1][kt], O[1][dt], 0, 0, 0);
      }
    }
    __builtin_amdgcn_s_setprio(0);
  }

  // epilogue: l = O4 row0 (lives at lg==0, reg 0, col=q) -> broadcast via shfl
#pragma unroll
  for (int qb = 0; qb < 2; ++qb) {
    float l = __shfl(O4[qb][0], lr, 64);
    float inv = 1.0f / l;
    int s = q0 + wave * 32 + qb * 16 + lr;
    size_t rowb = ((size_t)b * S_ + s) * HID_ + h * HD_;
#pragma unroll
    for (int dt = 0; dt < 4; ++dt) {
      float4 r;
      r.x = O[qb][dt][0] * inv;
      r.y = O[qb][dt][1] * inv;
      r.z = O[qb][dt][2] * inv;
      r.w = O[qb][dt][3] * inv;
      *(float4*)&outp[rowb + dt * 16 + lg * 4] = r;
    }
  }
}

}  // namespace

extern "C" void kernel_launch(void* const* d_in, const int* in_sizes, int n_in,
                              void* d_out, int out_size, void* d_ws, size_t ws_size,
                              hipStream_t stream) {
  const float* hs   = (const float*)d_in[0];
  const float* mask = (const float*)d_in[1];
  const float* Wq   = (const float*)d_in[2];
  const float* bq   = (const float*)d_in[3];
  const float* Wk   = (const float*)d_in[4];
  const float* bk   = (const float*)d_in[5];
  const float* Wv   = (const float*)d_in[6];
  const float* bv   = (const float*)d_in[7];

  u16* qw = (u16*)d_ws;                  // [B,NH,S,HD] bf16 (rope + scale*log2e)
  u16* kw = qw + QSZ;                    // [B,NH,S,HD] bf16 (rope)
  u16* vt = kw + QSZ;                    // [B,NH,HD,S] bf16
  u16* hh = vt + QSZ;                    // [M, HID] bf16
  u16* wt = hh + (size_t)M_ * HID_;      // [3][1024][1024] transposed bf16
  float* ct = (float*)(wt + (size_t)3 * 1024 * 1024);
  float* st = ct + TBL;

  prep_kernel<<<5120, 256, 0, stream>>>(hs, hh, Wq, Wk, Wv, wt, ct, st);

  proj_gemm_kernel<<<768, 256, 0, stream>>>(hh, wt, bq, bk, bv, ct, st, qw, kw, vt);

  attn_mfma_kernel<<<512, 256, 0, stream>>>(qw, kw, vt, mask, (float*)d_out);
}